// Round 1
// baseline (416.840 us; speedup 1.0000x reference)
//
#include <hip/hip_runtime.h>

#define C_CH 32
#define N 96
#define NN (N * N)
#define NNN (N * N * N)

#define TW 32
#define TH 8
#define TD 4
#define HW (TW + 2)            // 34
#define HH (TH + 2)            // 10
#define HD (TD + 2)            // 6
#define HALO (HD * HH * HW)    // 2040
#define NTHREADS (TW * TH * TD) // 1024

__global__ __launch_bounds__(NTHREADS) void wincorr_kernel(
    const float* __restrict__ fixedp,
    const float* __restrict__ movingp,
    float* __restrict__ outp)
{
    __shared__ float sm[HALO];

    const int tx = threadIdx.x;               // w in [0,32)
    const int ty = threadIdx.y;               // h in [0,8)
    const int tz = threadIdx.z;               // d in [0,4)
    const int tid = tx + TW * ty + TW * TH * tz;

    const int w0 = blockIdx.x * TW;
    const int h0 = blockIdx.y * TH;
    const int d0 = blockIdx.z * TD;

    const int gw = w0 + tx;
    const int gh = h0 + ty;
    const int gd = d0 + tz;

    // ---- precompute staging source offsets (channel-invariant) ----
    // halo element e covered by rounds e = tid and e = tid + NTHREADS
    int  src_off[2];
    bool src_ok[2];
    #pragma unroll
    for (int r = 0; r < 2; ++r) {
        const int e = tid + r * NTHREADS;
        if (e < HALO) {
            const int z   = e / (HH * HW);
            const int rem = e - z * (HH * HW);
            const int y   = rem / HW;
            const int x   = rem - y * HW;
            const int sd = d0 - 1 + z;
            const int sh = h0 - 1 + y;
            const int sw = w0 - 1 + x;
            const bool ok = (unsigned)sd < N && (unsigned)sh < N && (unsigned)sw < N;
            src_ok[r]  = ok;
            src_off[r] = ok ? ((sd * N + sh) * N + sw) : 0;
        } else {
            src_ok[r]  = false;
            src_off[r] = 0;
        }
    }

    float acc[27];
    #pragma unroll
    for (int s = 0; s < 27; ++s) acc[s] = 0.0f;

    const int fix_base  = (gd * N + gh) * N + gw;
    const int lds_base  = tz * (HH * HW) + ty * HW + tx;

    for (int c = 0; c < C_CH; ++c) {
        __syncthreads();
        const float* mc = movingp + (size_t)c * NNN;
        // stage halo tile of this channel
        sm[tid] = src_ok[0] ? mc[src_off[0]] : 0.0f;
        if (tid + NTHREADS < HALO) {
            sm[tid + NTHREADS] = src_ok[1] ? mc[src_off[1]] : 0.0f;
        }
        __syncthreads();

        const float f = fixedp[(size_t)c * NNN + fix_base];

        #pragma unroll
        for (int i = 0; i < 3; ++i)
            #pragma unroll
            for (int j = 0; j < 3; ++j)
                #pragma unroll
                for (int k = 0; k < 3; ++k)
                    acc[(i * 3 + j) * 3 + k] +=
                        f * sm[lds_base + i * (HH * HW) + j * HW + k];
    }

    const float scale = 0.17677669529663687f; // 32^-0.5
    #pragma unroll
    for (int s = 0; s < 27; ++s) {
        outp[(size_t)s * NNN + fix_base] = acc[s] * scale;
    }
}

extern "C" void kernel_launch(void* const* d_in, const int* in_sizes, int n_in,
                              void* d_out, int out_size, void* d_ws, size_t ws_size,
                              hipStream_t stream) {
    const float* fixedp  = (const float*)d_in[0];
    const float* movingp = (const float*)d_in[1];
    float* outp = (float*)d_out;

    dim3 block(TW, TH, TD);                  // 32 x 8 x 4 = 1024
    dim3 grid(N / TW, N / TH, N / TD);       // 3 x 12 x 24 = 864
    wincorr_kernel<<<grid, block, 0, stream>>>(fixedp, movingp, outp);
}

// Round 3
// 292.839 us; speedup vs baseline: 1.4234x; 1.4234x over previous
//
#include <hip/hip_runtime.h>

#define N 96
#define NNN (N * N * N)
#define C_CH 32

// tile geometry: block 8x8x4 = 256 threads, each thread computes 4 voxels along w
#define TXD 8
#define TYD 8
#define TZD 4
#define VX 4
#define TW (TXD * VX)          // 32
#define TH TYD                 // 8
#define TD TZD                 // 4

// halo tile in LDS: 34 x 10 x 6, row padded to 35 (odd stride -> 2-way bank = free)
#define HWS 35
#define HH 10
#define HD 6
#define PLANE (HWS * HH)       // 350
#define HTOT (PLANE * HD)      // 2100
#define NTH (TXD * TYD * TZD)  // 256
#define NR ((HTOT + NTH - 1) / NTH)  // 9 staging rounds
#define SMSZ (NR * NTH)        // 2304 (over-allocated so stores are unconditional)

__global__ __launch_bounds__(NTH, 3) void wincorr_kernel(
    const float* __restrict__ fixedp,
    const float* __restrict__ movingp,
    float* __restrict__ outp)
{
    __shared__ float sm[SMSZ];

    const int tx = threadIdx.x;   // 0..7  (w / 4)
    const int ty = threadIdx.y;   // 0..7  (h)
    const int tz = threadIdx.z;   // 0..3  (d)
    const int tid = tx + TXD * ty + TXD * TYD * tz;

    const int w0 = blockIdx.x * TW;
    const int h0 = blockIdx.y * TH;
    const int d0 = blockIdx.z * TD;

    // ---- channel-invariant staging source offsets ----
    // storage word a = tid + r*NTH maps to (z,y,x) with x-stride 1, row stride 35
    int off[NR];
    #pragma unroll
    for (int r = 0; r < NR; ++r) {
        const int a = tid + r * NTH;
        const int z   = a / PLANE;
        const int rm  = a - z * PLANE;
        const int y   = rm / HWS;
        const int x   = rm - y * HWS;
        const int sd = d0 - 1 + z;
        const int sh = h0 - 1 + y;
        const int sw = w0 - 1 + x;
        const bool ok = (a < HTOT) && (x < 34) &&
                        ((unsigned)sd < N) && ((unsigned)sh < N) && ((unsigned)sw < N);
        off[r] = ok ? ((sd * N + sh) * N + sw) : -1;
    }

    const int gw = w0 + VX * tx;
    const int fix_base = ((d0 + tz) * N + (h0 + ty)) * N + gw;
    const int lbase = tz * PLANE + ty * HWS + VX * tx;

    float acc[27][VX];
    #pragma unroll
    for (int s = 0; s < 27; ++s)
        #pragma unroll
        for (int v = 0; v < VX; ++v) acc[s][v] = 0.0f;

    // ---- prologue: prefetch channel 0 ----
    float st[NR];
    #pragma unroll
    for (int r = 0; r < NR; ++r)
        st[r] = (off[r] >= 0) ? movingp[off[r]] : 0.0f;
    float4 fnext = *(const float4*)&fixedp[fix_base];

    for (int c = 0; c < C_CH; ++c) {
        __syncthreads();   // previous iteration's LDS reads complete
        #pragma unroll
        for (int r = 0; r < NR; ++r)
            sm[tid + r * NTH] = st[r];
        __syncthreads();

        const float4 f = fnext;
        const float fv[VX] = {f.x, f.y, f.z, f.w};

        // prefetch next channel while computing this one (loads stay in flight)
        if (c + 1 < C_CH) {
            const float* mnext = movingp + (size_t)(c + 1) * NNN;
            #pragma unroll
            for (int r = 0; r < NR; ++r)
                st[r] = (off[r] >= 0) ? mnext[off[r]] : 0.0f;
            fnext = *(const float4*)&fixedp[(size_t)(c + 1) * NNN + fix_base];
        }

        // compute: 9 rows x 6-float sliding window, 27 taps x 4 voxels
        #pragma unroll
        for (int i = 0; i < 3; ++i) {
            #pragma unroll
            for (int j = 0; j < 3; ++j) {
                const float* row = &sm[lbase + i * PLANE + j * HWS];
                float wv[VX + 2];
                #pragma unroll
                for (int m = 0; m < VX + 2; ++m) wv[m] = row[m];
                #pragma unroll
                for (int k = 0; k < 3; ++k)
                    #pragma unroll
                    for (int v = 0; v < VX; ++v)
                        acc[(i * 3 + j) * 3 + k][v] += fv[v] * wv[v + k];
            }
        }
    }

    const float scale = 0.17677669529663687f; // 32^-0.5
    #pragma unroll
    for (int s = 0; s < 27; ++s) {
        float4 o;
        o.x = acc[s][0] * scale;
        o.y = acc[s][1] * scale;
        o.z = acc[s][2] * scale;
        o.w = acc[s][3] * scale;
        *(float4*)&outp[(size_t)s * NNN + fix_base] = o;
    }
}

extern "C" void kernel_launch(void* const* d_in, const int* in_sizes, int n_in,
                              void* d_out, int out_size, void* d_ws, size_t ws_size,
                              hipStream_t stream) {
    const float* fixedp  = (const float*)d_in[0];
    const float* movingp = (const float*)d_in[1];
    float* outp = (float*)d_out;

    dim3 block(TXD, TYD, TZD);                    // 8 x 8 x 4 = 256
    dim3 grid(N / TW, N / TH, N / TD);            // 3 x 12 x 24 = 864
    wincorr_kernel<<<grid, block, 0, stream>>>(fixedp, movingp, outp);
}